// Round 5
// baseline (3349.883 us; speedup 1.0000x reference)
//
#include <hip/hip_runtime.h>
#include <math.h>

#define VSZ 32000
#define DM  768
#define NH  12
#define DHD 64
#define NL  12
#define BB  4
#define TT  512
#define BTT 2048          // B*T
#define D3  2304          // 3*D
#define EPSF 1e-5f
#define SCALE_ATT 0.03608439182435161f   // 1/sqrt(768)  (reference scales by sqrt(d_model))

typedef __attribute__((ext_vector_type(8))) short bf16x8;
typedef __attribute__((ext_vector_type(4))) float f32x4;

__device__ __forceinline__ unsigned short f2b(float f) {
    unsigned u = __float_as_uint(f);
    unsigned r = u + 0x7fffu + ((u >> 16) & 1u);   // round-to-nearest-even
    return (unsigned short)(r >> 16);
}

// ---------------------------------------------------------------------------
// x[b,t,:] = embed[token] + sinusoidal positional embedding
// ---------------------------------------------------------------------------
__global__ __launch_bounds__(256) void embed_pos_kernel(
        const int* __restrict__ tokens, const float* __restrict__ embed,
        float* __restrict__ x) {
    int row = blockIdx.x;            // b*T + t
    int t   = row % TT;
    int tok = tokens[row];
    const float* erow = embed + (size_t)tok * DM;
    float* xrow = x + (size_t)row * DM;
    const float LOG2_10000 = 13.287712379549449f;
    for (int c = threadIdx.x; c < DM; c += 256) {
        int c2 = c & ~1;
        float inv = exp2f(-(float)c2 * (LOG2_10000 / (float)DM));
        float ang = (float)t * inv;
        float pe  = (c & 1) ? cosf(ang) : sinf(ang);
        xrow[c] = erow[c] + pe;
    }
}

// ---------------------------------------------------------------------------
// f32 -> bf16 elementwise (n multiple of 2048); 8 elements/thread
// ---------------------------------------------------------------------------
__global__ __launch_bounds__(256) void convert_bf16_kernel(
        const float* __restrict__ in, unsigned short* __restrict__ out) {
    int idx = (blockIdx.x * 256 + threadIdx.x) * 8;
    float4 v0 = *(const float4*)(in + idx);
    float4 v1 = *(const float4*)(in + idx + 4);
    unsigned p0 = (unsigned)f2b(v0.x) | ((unsigned)f2b(v0.y) << 16);
    unsigned p1 = (unsigned)f2b(v0.z) | ((unsigned)f2b(v0.w) << 16);
    unsigned p2 = (unsigned)f2b(v1.x) | ((unsigned)f2b(v1.y) << 16);
    unsigned p3 = (unsigned)f2b(v1.z) | ((unsigned)f2b(v1.w) << 16);
    uint4 o = make_uint4(p0, p1, p2, p3);
    *(uint4*)(out + idx) = o;
}

// ---------------------------------------------------------------------------
// Transpose + convert: in f32 [K][N] row-major -> out bf16 [N][K] row-major.
// 64x64 tiles via LDS. Grid: (N/64, K/64).
// ---------------------------------------------------------------------------
__global__ __launch_bounds__(256) void transconv_kernel(
        const float* __restrict__ in, unsigned short* __restrict__ out,
        int K, int N) {
    __shared__ float tile[64][65];
    const int k0 = blockIdx.y * 64, n0 = blockIdx.x * 64;
    const int t = threadIdx.x;
    const int lr = t >> 4, lc4 = (t & 15) * 4;
    #pragma unroll
    for (int i = 0; i < 4; ++i) {
        float4 v = *(const float4*)(in + (size_t)(k0 + lr + 16 * i) * N + n0 + lc4);
        tile[lr + 16 * i][lc4 + 0] = v.x; tile[lr + 16 * i][lc4 + 1] = v.y;
        tile[lr + 16 * i][lc4 + 2] = v.z; tile[lr + 16 * i][lc4 + 3] = v.w;
    }
    __syncthreads();
    #pragma unroll
    for (int i = 0; i < 2; ++i) {
        int c = t + 256 * i;
        int orow = c >> 3;            // n-local
        int oc8 = (c & 7) * 8;        // k-local start
        unsigned p[4];
        #pragma unroll
        for (int j = 0; j < 4; ++j) {
            unsigned short lo = f2b(tile[oc8 + 2 * j][orow]);
            unsigned short hi = f2b(tile[oc8 + 2 * j + 1][orow]);
            p[j] = (unsigned)lo | ((unsigned)hi << 16);
        }
        uint4 o = make_uint4(p[0], p[1], p[2], p[3]);
        *(uint4*)(out + (size_t)(n0 + orow) * K + k0 + oc8) = o;
    }
}

// ---------------------------------------------------------------------------
// Repack+convert Wq/Wk/Wv (layer l) into wqkvT bf16 [2304][768]:
//   wqkvT[j][d], j = which*768 + h*64 + e
// ---------------------------------------------------------------------------
__global__ __launch_bounds__(256) void repack_qkvT_kernel(
        const float* __restrict__ Wq, const float* __restrict__ Wk,
        const float* __restrict__ Wv, unsigned short* __restrict__ out, int layer) {
    int idx = blockIdx.x * 256 + threadIdx.x;      // over 2304*96
    int j = idx / 96;
    int d0 = (idx % 96) * 8;
    int which = j / DM, jj = j % DM;
    int h = jj >> 6, e = jj & 63;
    const float* W = (which == 0) ? Wq : (which == 1) ? Wk : Wv;
    const float* base = W + ((size_t)(layer * NH + h) * DM) * DHD + e;
    unsigned p[4];
    #pragma unroll
    for (int u = 0; u < 4; ++u) {
        unsigned short lo = f2b(base[(size_t)(d0 + 2 * u) * DHD]);
        unsigned short hi = f2b(base[(size_t)(d0 + 2 * u + 1) * DHD]);
        p[u] = (unsigned)lo | ((unsigned)hi << 16);
    }
    uint4 o = make_uint4(p[0], p[1], p[2], p[3]);
    *(uint4*)(out + (size_t)j * DM + d0) = o;
}

// ---------------------------------------------------------------------------
// bf16 MFMA GEMM: C[M,N] (f32) = A[M,K](bf16) * BT[N,K](bf16)^T + bias
// 128x128 tile, BK=64, 256 threads (4 waves in 2x2 quadrants of 64x64),
// mfma_f32_16x16x32_bf16, 16B-chunk XOR swizzle on LDS (T2).
// Requires M,N multiples of 128; K multiple of 64.
// ---------------------------------------------------------------------------
template<bool RELU, bool BIAS>
__global__ __launch_bounds__(256) void gemm_mfma_kernel(
        const unsigned short* __restrict__ A,
        const unsigned short* __restrict__ BT,
        float* __restrict__ C, const float* __restrict__ bias,
        int M, int N, int K) {
    __shared__ __align__(16) unsigned short As[128 * 64];
    __shared__ __align__(16) unsigned short Bs[128 * 64];
    const int tid = threadIdx.x;
    const int bm0 = blockIdx.y * 128, bn0 = blockIdx.x * 128;
    const int lane = tid & 63;
    const int wave = tid >> 6;
    const int wr = (wave >> 1) * 64;     // wave row offset in tile
    const int wc = (wave & 1) * 64;      // wave col offset in tile
    const int l15 = lane & 15, g = lane >> 4;

    f32x4 acc[4][4] = {};

    for (int k0 = 0; k0 < K; k0 += 64) {
        #pragma unroll
        for (int i = 0; i < 4; ++i) {
            int c = tid + 256 * i;          // 0..1023 16B-chunks
            int row = c >> 3;               // 0..127
            int col = c & 7;                // 16B chunk within row
            int sc = col ^ (row & 7);       // XOR swizzle
            uint4 va = *(const uint4*)(A + (size_t)(bm0 + row) * K + k0 + col * 8);
            *(uint4*)(&As[row * 64 + sc * 8]) = va;
            uint4 vb = *(const uint4*)(BT + (size_t)(bn0 + row) * K + k0 + col * 8);
            *(uint4*)(&Bs[row * 64 + sc * 8]) = vb;
        }
        __syncthreads();

        #pragma unroll
        for (int ks = 0; ks < 2; ++ks) {
            bf16x8 a[4], b[4];
            #pragma unroll
            for (int i = 0; i < 4; ++i) {
                int arow = wr + i * 16 + l15;
                int ac = (ks * 4 + g) ^ (arow & 7);
                a[i] = *(const bf16x8*)(&As[arow * 64 + ac * 8]);
                int brow = wc + i * 16 + l15;
                int bc = (ks * 4 + g) ^ (brow & 7);
                b[i] = *(const bf16x8*)(&Bs[brow * 64 + bc * 8]);
            }
            #pragma unroll
            for (int i = 0; i < 4; ++i)
                #pragma unroll
                for (int j = 0; j < 4; ++j)
                    acc[i][j] = __builtin_amdgcn_mfma_f32_16x16x32_bf16(
                        a[i], b[j], acc[i][j], 0, 0, 0);
        }
        __syncthreads();
    }

    // C/D layout (verified m89/m91): col = lane&15, row = (lane>>4)*4 + reg
    #pragma unroll
    for (int i = 0; i < 4; ++i) {
        #pragma unroll
        for (int j = 0; j < 4; ++j) {
            int col = bn0 + wc + j * 16 + l15;
            float bv = BIAS ? bias[col] : 0.0f;
            #pragma unroll
            for (int r = 0; r < 4; ++r) {
                int row = bm0 + wr + i * 16 + g * 4 + r;
                float v = acc[i][j][r] + bv;
                if (RELU) v = fmaxf(v, 0.0f);
                C[(size_t)row * N + col] = v;
            }
        }
    }
}

// ---------------------------------------------------------------------------
// Attention scores (f32): S = scale * q.k on lower-triangle 64x64 tiles
// ---------------------------------------------------------------------------
__global__ __launch_bounds__(256) void attn_scores_kernel(
        const float* __restrict__ qkv, float* __restrict__ scores) {
    const int mt = blockIdx.x;
    const int nt = blockIdx.y;
    if (nt > mt) return;
    const int bh = blockIdx.z;
    const int b = bh / NH, h = bh % NH;

    __shared__ float Qs[64][65];
    __shared__ float Ks[64][65];

    const float* qbase = qkv + (size_t)(b * TT) * D3 + h * DHD;
    const float* kbase = qbase + DM;

    const int lr = threadIdx.x >> 2;
    const int lc = (threadIdx.x & 3) * 16;
    const float* qrow = qbase + (size_t)(mt * 64 + lr) * D3 + lc;
    const float* krow = kbase + (size_t)(nt * 64 + lr) * D3 + lc;
    #pragma unroll
    for (int u = 0; u < 4; ++u) {
        float4 qv = *(const float4*)(qrow + 4 * u);
        Qs[lr][lc + 4 * u + 0] = qv.x; Qs[lr][lc + 4 * u + 1] = qv.y;
        Qs[lr][lc + 4 * u + 2] = qv.z; Qs[lr][lc + 4 * u + 3] = qv.w;
        float4 kv = *(const float4*)(krow + 4 * u);
        Ks[lr][lc + 4 * u + 0] = kv.x; Ks[lr][lc + 4 * u + 1] = kv.y;
        Ks[lr][lc + 4 * u + 2] = kv.z; Ks[lr][lc + 4 * u + 3] = kv.w;
    }
    __syncthreads();

    const int tx = threadIdx.x & 15;
    const int ty = threadIdx.x >> 4;
    float acc[4][4] = {};
    #pragma unroll 8
    for (int kk = 0; kk < 64; ++kk) {
        float a[4], bv[4];
        #pragma unroll
        for (int i = 0; i < 4; ++i) a[i] = Qs[ty + 16 * i][kk];
        #pragma unroll
        for (int j = 0; j < 4; ++j) bv[j] = Ks[tx + 16 * j][kk];
        #pragma unroll
        for (int i = 0; i < 4; ++i)
            #pragma unroll
            for (int j = 0; j < 4; ++j)
                acc[i][j] = fmaf(a[i], bv[j], acc[i][j]);
    }

    float* srow = scores + (size_t)bh * TT * TT;
    #pragma unroll
    for (int i = 0; i < 4; ++i)
        #pragma unroll
        for (int j = 0; j < 4; ++j)
            srow[(size_t)(mt * 64 + ty + 16 * i) * TT + nt * 64 + tx + 16 * j] =
                acc[i][j] * SCALE_ATT;
}

// ---------------------------------------------------------------------------
// Row softmax over s in [0,t]; zero-fills to next 64 boundary.
// ---------------------------------------------------------------------------
__global__ __launch_bounds__(256) void attn_softmax_kernel(float* __restrict__ scores) {
    const int row = blockIdx.x;
    const int t = row % TT;
    float* p = scores + (size_t)row * TT;
    const int n = t + 1;
    __shared__ float red[256];

    float lmax = -INFINITY;
    for (int s = threadIdx.x; s < n; s += 256) lmax = fmaxf(lmax, p[s]);
    red[threadIdx.x] = lmax; __syncthreads();
    for (int off = 128; off > 0; off >>= 1) {
        if (threadIdx.x < off) red[threadIdx.x] = fmaxf(red[threadIdx.x], red[threadIdx.x + off]);
        __syncthreads();
    }
    const float m = red[0]; __syncthreads();

    float lsum = 0.0f;
    for (int s = threadIdx.x; s < n; s += 256) {
        float e = expf(p[s] - m);
        p[s] = e; lsum += e;
    }
    red[threadIdx.x] = lsum; __syncthreads();
    for (int off = 128; off > 0; off >>= 1) {
        if (threadIdx.x < off) red[threadIdx.x] += red[threadIdx.x + off];
        __syncthreads();
    }
    const float inv = 1.0f / red[0];

    for (int s = threadIdx.x; s < n; s += 256) p[s] *= inv;
    const int lim = (t / 64 + 1) * 64;
    for (int s = n + threadIdx.x; s < lim; s += 256) p[s] = 0.0f;
}

// ---------------------------------------------------------------------------
// PV (f32): a[b,t,h*64+e] = sum_s P[t,s] * V[s,e]
// ---------------------------------------------------------------------------
__global__ __launch_bounds__(256) void attn_pv_kernel(
        const float* __restrict__ scores, const float* __restrict__ qkv,
        float* __restrict__ attn) {
    const int mt = blockIdx.x;
    const int bh = blockIdx.y;
    const int b = bh / NH, h = bh % NH;
    const float* P = scores + (size_t)bh * TT * TT;
    const float* vbase = qkv + (size_t)(b * TT) * D3 + 2 * DM + h * DHD;

    __shared__ float Ps[16][65];
    __shared__ float Vs[16][64];

    const int tx = threadIdx.x & 15;
    const int ty = threadIdx.x >> 4;
    float acc[4][4] = {};

    const int lp_m = threadIdx.x >> 2;
    const int lp_k = (threadIdx.x & 3) * 4;
    const int lv_k = threadIdx.x >> 4;
    const int lv_n = (threadIdx.x & 15) * 4;

    const int Klen = (mt + 1) * 64;
    for (int k0 = 0; k0 < Klen; k0 += 16) {
        float4 pv = *(const float4*)(P + (size_t)(mt * 64 + lp_m) * TT + k0 + lp_k);
        Ps[lp_k + 0][lp_m] = pv.x; Ps[lp_k + 1][lp_m] = pv.y;
        Ps[lp_k + 2][lp_m] = pv.z; Ps[lp_k + 3][lp_m] = pv.w;
        float4 vv = *(const float4*)(vbase + (size_t)(k0 + lv_k) * D3 + lv_n);
        *(float4*)&Vs[lv_k][lv_n] = vv;
        __syncthreads();
        #pragma unroll
        for (int kk = 0; kk < 16; ++kk) {
            float a[4], bv[4];
            #pragma unroll
            for (int i = 0; i < 4; ++i) a[i] = Ps[kk][ty + 16 * i];
            #pragma unroll
            for (int j = 0; j < 4; ++j) bv[j] = Vs[kk][tx + 16 * j];
            #pragma unroll
            for (int i = 0; i < 4; ++i)
                #pragma unroll
                for (int j = 0; j < 4; ++j)
                    acc[i][j] = fmaf(a[i], bv[j], acc[i][j]);
        }
        __syncthreads();
    }

    #pragma unroll
    for (int i = 0; i < 4; ++i) {
        int trow = b * TT + mt * 64 + ty + 16 * i;
        float* arow = attn + (size_t)trow * DM + h * DHD;
        #pragma unroll
        for (int j = 0; j < 4; ++j) arow[tx + 16 * j] = acc[i][j];
    }
}

// ---------------------------------------------------------------------------
// x[row] += LayerNorm(tin[row]) * g + b
// ---------------------------------------------------------------------------
__global__ __launch_bounds__(256) void ln_residual_kernel(
        float* __restrict__ x, const float* __restrict__ tin,
        const float* __restrict__ g, const float* __restrict__ b) {
    const int row = blockIdx.x;
    const float* tr = tin + (size_t)row * DM;
    const int c0 = threadIdx.x;
    float v0 = tr[c0], v1 = tr[c0 + 256], v2 = tr[c0 + 512];
    __shared__ float red[256];

    red[threadIdx.x] = v0 + v1 + v2; __syncthreads();
    for (int off = 128; off > 0; off >>= 1) {
        if (threadIdx.x < off) red[threadIdx.x] += red[threadIdx.x + off];
        __syncthreads();
    }
    const float mean = red[0] * (1.0f / DM); __syncthreads();

    float d0 = v0 - mean, d1 = v1 - mean, d2 = v2 - mean;
    red[threadIdx.x] = d0 * d0 + d1 * d1 + d2 * d2; __syncthreads();
    for (int off = 128; off > 0; off >>= 1) {
        if (threadIdx.x < off) red[threadIdx.x] += red[threadIdx.x + off];
        __syncthreads();
    }
    const float var = red[0] * (1.0f / DM);
    const float inv = 1.0f / sqrtf(var + EPSF);

    float* xr = x + (size_t)row * DM;
    xr[c0]       += d0 * inv * g[c0]       + b[c0];
    xr[c0 + 256] += d1 * inv * g[c0 + 256] + b[c0 + 256];
    xr[c0 + 512] += d2 * inv * g[c0 + 512] + b[c0 + 512];
}

// ---------------------------------------------------------------------------
extern "C" void kernel_launch(void* const* d_in, const int* in_sizes, int n_in,
                              void* d_out, int out_size, void* d_ws, size_t ws_size,
                              hipStream_t stream) {
    const int*   tokens = (const int*)d_in[0];
    const float* embed  = (const float*)d_in[1];
    const float* Wq  = (const float*)d_in[2];
    const float* Wk  = (const float*)d_in[3];
    const float* Wv  = (const float*)d_in[4];
    const float* Wo  = (const float*)d_in[5];
    const float* bo  = (const float*)d_in[6];
    const float* g1  = (const float*)d_in[7];
    const float* b1  = (const float*)d_in[8];
    const float* W1  = (const float*)d_in[9];
    const float* bf1 = (const float*)d_in[10];
    const float* W2  = (const float*)d_in[11];
    const float* bf2 = (const float*)d_in[12];
    const float* g2  = (const float*)d_in[13];
    const float* b2  = (const float*)d_in[14];
    const float* Wout = (const float*)d_in[15];
    const float* bout = (const float*)d_in[16];
    float* out = (float*)d_out;

    // f32 buffers
    float* x      = (float*)d_ws;                       // [2048][768]
    float* qkv    = x      + (size_t)BTT * DM;          // [2048][2304]
    float* scores = qkv    + (size_t)BTT * D3;          // [48][512][512] (50.3MB)
    float* attn   = scores + (size_t)BB * NH * TT * TT; // [2048][768]
    float* t1     = attn   + (size_t)BTT * DM;          // [2048][768]
    float* t2     = t1     + (size_t)BTT * DM;          // [2048][768]
    // bf16 buffers
    unsigned short* xb      = (unsigned short*)(t2 + (size_t)BTT * DM); // [2048][768]
    unsigned short* ab      = xb + (size_t)BTT * DM;     // [2048][768]
    unsigned short* tb      = ab + (size_t)BTT * DM;     // [2048][768]
    unsigned short* wqkvT   = tb + (size_t)BTT * DM;     // [2304][768]
    unsigned short* woT     = wqkvT + (size_t)D3 * DM;   // [768][768]
    unsigned short* w1T     = woT + (size_t)DM * DM;     // [768][768]
    unsigned short* w2T     = w1T + (size_t)DM * DM;     // [768][768]
    // WoutT [32000][768] bf16 (49.2MB) overlays scores (50.3MB; dead after loop)
    unsigned short* woutT   = (unsigned short*)scores;

    const int CONV_BT = (BTT * DM) / 2048;   // 768 blocks (8 elems/thread)

    embed_pos_kernel<<<BTT, 256, 0, stream>>>(tokens, embed, x);

    for (int l = 0; l < NL; ++l) {
        // QKV projection (bf16 MFMA)
        convert_bf16_kernel<<<CONV_BT, 256, 0, stream>>>(x, xb);
        repack_qkvT_kernel<<<(D3 * 96) / 256, 256, 0, stream>>>(Wq, Wk, Wv, wqkvT, l);
        gemm_mfma_kernel<false, false><<<dim3(D3 / 128, BTT / 128), 256, 0, stream>>>(
            xb, wqkvT, qkv, nullptr, BTT, D3, DM);
        // Attention (f32)
        attn_scores_kernel<<<dim3(8, 8, BB * NH), 256, 0, stream>>>(qkv, scores);
        attn_softmax_kernel<<<BB * NH * TT, 256, 0, stream>>>(scores);
        attn_pv_kernel<<<dim3(8, BB * NH), 256, 0, stream>>>(scores, qkv, attn);
        // Output projection
        convert_bf16_kernel<<<CONV_BT, 256, 0, stream>>>(attn, ab);
        transconv_kernel<<<dim3(DM / 64, DM / 64), 256, 0, stream>>>(
            Wo + (size_t)l * DM * DM, woT, DM, DM);
        gemm_mfma_kernel<false, true><<<dim3(DM / 128, BTT / 128), 256, 0, stream>>>(
            ab, woT, t1, bo + (size_t)l * DM, BTT, DM, DM);
        ln_residual_kernel<<<BTT, 256, 0, stream>>>(x, t1, g1 + (size_t)l * DM, b1 + (size_t)l * DM);
        // FFN
        convert_bf16_kernel<<<CONV_BT, 256, 0, stream>>>(x, xb);
        transconv_kernel<<<dim3(DM / 64, DM / 64), 256, 0, stream>>>(
            W1 + (size_t)l * DM * DM, w1T, DM, DM);
        gemm_mfma_kernel<true, true><<<dim3(DM / 128, BTT / 128), 256, 0, stream>>>(
            xb, w1T, t1, bf1 + (size_t)l * DM, BTT, DM, DM);
        convert_bf16_kernel<<<CONV_BT, 256, 0, stream>>>(t1, tb);
        transconv_kernel<<<dim3(DM / 64, DM / 64), 256, 0, stream>>>(
            W2 + (size_t)l * DM * DM, w2T, DM, DM);
        gemm_mfma_kernel<false, true><<<dim3(DM / 128, BTT / 128), 256, 0, stream>>>(
            tb, w2T, t2, bf2 + (size_t)l * DM, BTT, DM, DM);
        ln_residual_kernel<<<BTT, 256, 0, stream>>>(x, t2, g2 + (size_t)l * DM, b2 + (size_t)l * DM);
    }

    // Final vocab projection (scores buffer is dead; reuse as WoutT)
    convert_bf16_kernel<<<CONV_BT, 256, 0, stream>>>(x, xb);
    transconv_kernel<<<dim3(VSZ / 64, DM / 64), 256, 0, stream>>>(Wout, woutT, DM, VSZ);
    gemm_mfma_kernel<false, true><<<dim3(VSZ / 128, BTT / 128), 256, 0, stream>>>(
        xb, woutT, out, bout, BTT, VSZ, DM);
}

// Round 7
// 2154.380 us; speedup vs baseline: 1.5549x; 1.5549x over previous
//
#include <hip/hip_runtime.h>
#include <math.h>

#define VSZ 32000
#define DM  768
#define NH  12
#define DHD 64
#define NL  12
#define BB  4
#define TT  512
#define BTT 2048          // B*T
#define D3  2304          // 3*D
#define EPSF 1e-5f
#define SCALE_ATT 0.03608439182435161f   // 1/sqrt(768)  (reference scales by sqrt(d_model))

typedef __attribute__((ext_vector_type(8))) short bf16x8;
typedef __attribute__((ext_vector_type(4))) float f32x4;

__device__ __forceinline__ unsigned short f2b(float f) {
    unsigned u = __float_as_uint(f);
    unsigned r = u + 0x7fffu + ((u >> 16) & 1u);   // round-to-nearest-even
    return (unsigned short)(r >> 16);
}

// ---------------------------------------------------------------------------
// x[b,t,:] = embed[token] + pos;  also writes bf16 copy
// ---------------------------------------------------------------------------
__global__ __launch_bounds__(256) void embed_pos_kernel(
        const int* __restrict__ tokens, const float* __restrict__ embed,
        float* __restrict__ x, unsigned short* __restrict__ xb) {
    int row = blockIdx.x;            // b*T + t
    int t   = row % TT;
    int tok = tokens[row];
    const float* erow = embed + (size_t)tok * DM;
    float* xrow = x + (size_t)row * DM;
    unsigned short* xbrow = xb + (size_t)row * DM;
    const float LOG2_10000 = 13.287712379549449f;
    for (int c = threadIdx.x; c < DM; c += 256) {
        int c2 = c & ~1;
        float inv = exp2f(-(float)c2 * (LOG2_10000 / (float)DM));
        float ang = (float)t * inv;
        float pe  = (c & 1) ? cosf(ang) : sinf(ang);
        float v = erow[c] + pe;
        xrow[c] = v;
        xbrow[c] = f2b(v);
    }
}

// ---------------------------------------------------------------------------
// Batched repack: Wq/Wk/Wv (ALL layers) -> wqkvT bf16 [L][2304][768]
// ---------------------------------------------------------------------------
__global__ __launch_bounds__(256) void repack_qkvT_all_kernel(
        const float* __restrict__ Wq, const float* __restrict__ Wk,
        const float* __restrict__ Wv, unsigned short* __restrict__ out) {
    int idx = blockIdx.x * 256 + threadIdx.x;      // over NL*2304*96
    int l = idx / (D3 * 96);
    int rem = idx % (D3 * 96);
    int j = rem / 96;
    int d0 = (rem % 96) * 8;
    int which = j / DM, jj = j % DM;
    int h = jj >> 6, e = jj & 63;
    const float* W = (which == 0) ? Wq : (which == 1) ? Wk : Wv;
    const float* base = W + ((size_t)(l * NH + h) * DM) * DHD + e;
    unsigned p[4];
    #pragma unroll
    for (int u = 0; u < 4; ++u) {
        unsigned short lo = f2b(base[(size_t)(d0 + 2 * u) * DHD]);
        unsigned short hi = f2b(base[(size_t)(d0 + 2 * u + 1) * DHD]);
        p[u] = (unsigned)lo | ((unsigned)hi << 16);
    }
    uint4 o = make_uint4(p[0], p[1], p[2], p[3]);
    *(uint4*)(out + ((size_t)l * D3 + j) * DM + d0) = o;
}

// ---------------------------------------------------------------------------
// Generic transpose+convert: f32 [K][N] -> bf16 [N][K]. Grid (N/64, K/64).
// ---------------------------------------------------------------------------
__device__ __forceinline__ void transconv_body(
        const float* __restrict__ in, unsigned short* __restrict__ out,
        int K, int N, int n0, int k0) {
    __shared__ float tile[64][65];
    const int t = threadIdx.x;
    const int lr = t >> 4, lc4 = (t & 15) * 4;
    #pragma unroll
    for (int i = 0; i < 4; ++i) {
        float4 v = *(const float4*)(in + (size_t)(k0 + lr + 16 * i) * N + n0 + lc4);
        tile[lr + 16 * i][lc4 + 0] = v.x; tile[lr + 16 * i][lc4 + 1] = v.y;
        tile[lr + 16 * i][lc4 + 2] = v.z; tile[lr + 16 * i][lc4 + 3] = v.w;
    }
    __syncthreads();
    #pragma unroll
    for (int i = 0; i < 2; ++i) {
        int c = t + 256 * i;
        int orow = c >> 3;
        int oc8 = (c & 7) * 8;
        unsigned p[4];
        #pragma unroll
        for (int j = 0; j < 4; ++j) {
            unsigned short lo = f2b(tile[oc8 + 2 * j][orow]);
            unsigned short hi = f2b(tile[oc8 + 2 * j + 1][orow]);
            p[j] = (unsigned)lo | ((unsigned)hi << 16);
        }
        uint4 o = make_uint4(p[0], p[1], p[2], p[3]);
        *(uint4*)(out + (size_t)(n0 + orow) * K + k0 + oc8) = o;
    }
}

__global__ __launch_bounds__(256) void transconv_kernel(
        const float* __restrict__ in, unsigned short* __restrict__ out,
        int K, int N) {
    transconv_body(in, out, K, N, blockIdx.x * 64, blockIdx.y * 64);
}

// Batched over Wo/W1/W2 x 12 layers: z = which*NL + l
__global__ __launch_bounds__(256) void transconv3_all_kernel(
        const float* __restrict__ Wo, const float* __restrict__ W1,
        const float* __restrict__ W2, unsigned short* __restrict__ woT,
        unsigned short* __restrict__ w1T, unsigned short* __restrict__ w2T) {
    int z = blockIdx.z;
    int which = z / NL, l = z % NL;
    const float* src = ((which == 0) ? Wo : (which == 1) ? W1 : W2) + (size_t)l * DM * DM;
    unsigned short* dst = ((which == 0) ? woT : (which == 1) ? w1T : w2T) + (size_t)l * DM * DM;
    transconv_body(src, dst, DM, DM, blockIdx.x * 64, blockIdx.y * 64);
}

// ---------------------------------------------------------------------------
// bf16 MFMA GEMM: C[M,N] = op(A[M,K](bf16) * BT[N,K](bf16)^T + bias)
// OBF16: C is bf16, else f32.  (layouts HW-validated in R5)
// ---------------------------------------------------------------------------
template<bool RELU, bool BIAS, bool OBF16>
__global__ __launch_bounds__(256) void gemm_mfma_kernel(
        const unsigned short* __restrict__ A,
        const unsigned short* __restrict__ BT,
        void* __restrict__ Cout, const float* __restrict__ bias,
        int M, int N, int K) {
    __shared__ __align__(16) unsigned short As[128 * 64];
    __shared__ __align__(16) unsigned short Bs[128 * 64];
    const int tid = threadIdx.x;
    const int bm0 = blockIdx.y * 128, bn0 = blockIdx.x * 128;
    const int lane = tid & 63;
    const int wave = tid >> 6;
    const int wr = (wave >> 1) * 64;
    const int wc = (wave & 1) * 64;
    const int l15 = lane & 15, g = lane >> 4;

    f32x4 acc[4][4] = {};

    for (int k0 = 0; k0 < K; k0 += 64) {
        #pragma unroll
        for (int i = 0; i < 4; ++i) {
            int c = tid + 256 * i;
            int row = c >> 3;
            int col = c & 7;
            int sc = col ^ (row & 7);
            uint4 va = *(const uint4*)(A + (size_t)(bm0 + row) * K + k0 + col * 8);
            *(uint4*)(&As[row * 64 + sc * 8]) = va;
            uint4 vb = *(const uint4*)(BT + (size_t)(bn0 + row) * K + k0 + col * 8);
            *(uint4*)(&Bs[row * 64 + sc * 8]) = vb;
        }
        __syncthreads();

        #pragma unroll
        for (int ks = 0; ks < 2; ++ks) {
            bf16x8 a[4], b[4];
            #pragma unroll
            for (int i = 0; i < 4; ++i) {
                int arow = wr + i * 16 + l15;
                int ac = (ks * 4 + g) ^ (arow & 7);
                a[i] = *(const bf16x8*)(&As[arow * 64 + ac * 8]);
                int brow = wc + i * 16 + l15;
                int bc = (ks * 4 + g) ^ (brow & 7);
                b[i] = *(const bf16x8*)(&Bs[brow * 64 + bc * 8]);
            }
            #pragma unroll
            for (int i = 0; i < 4; ++i)
                #pragma unroll
                for (int j = 0; j < 4; ++j)
                    acc[i][j] = __builtin_amdgcn_mfma_f32_16x16x32_bf16(
                        a[i], b[j], acc[i][j], 0, 0, 0);
        }
        __syncthreads();
    }

    #pragma unroll
    for (int i = 0; i < 4; ++i) {
        #pragma unroll
        for (int j = 0; j < 4; ++j) {
            int col = bn0 + wc + j * 16 + l15;
            float bv = BIAS ? bias[col] : 0.0f;
            #pragma unroll
            for (int r = 0; r < 4; ++r) {
                int row = bm0 + wr + i * 16 + g * 4 + r;
                float v = acc[i][j][r] + bv;
                if (RELU) v = fmaxf(v, 0.0f);
                if (OBF16) ((unsigned short*)Cout)[(size_t)row * N + col] = f2b(v);
                else       ((float*)Cout)[(size_t)row * N + col] = v;
            }
        }
    }
}

// ---------------------------------------------------------------------------
// Fused flash attention (bf16 MFMA, f32 online softmax).
// Block: 256 thr / 4 waves; grid (8 qtiles, 48 bh). Wave w owns Q rows
// q0=qt*64+w*16 .. +15. K/V tiles of 64 iterated causally.
// qkvb: [2048][2304] bf16 (q|k|v per head).  ab out: [2048][768] bf16.
// ---------------------------------------------------------------------------
__global__ __launch_bounds__(256) void attn_flash_kernel(
        const unsigned short* __restrict__ qkvb,
        unsigned short* __restrict__ ab) {
    __shared__ __align__(16) unsigned short Vt[64][72];      // V^T [e][s]
    __shared__ __align__(16) unsigned short Pl[4][16][72];   // per-wave P
    const int qt = blockIdx.x;
    const int bh = blockIdx.y;
    const int b = bh / NH, h = bh % NH;
    const int tid = threadIdx.x;
    const int wave = tid >> 6, lane = tid & 63;
    const int l15 = lane & 15, g = lane >> 4;
    const int q0 = qt * 64 + wave * 16;

    // Q A-frags (row = l15, d = dt*32 + g*8 + i)
    const unsigned short* qrow = qkvb + (size_t)(b * TT + q0 + l15) * D3 + h * DHD;
    bf16x8 qf0 = *(const bf16x8*)(qrow + g * 8);
    bf16x8 qf1 = *(const bf16x8*)(qrow + 32 + g * 8);

    f32x4 o[4] = {};          // 4 e-tiles, C-layout
    float m_[4], l_[4];
    #pragma unroll
    for (int r = 0; r < 4; ++r) { m_[r] = -INFINITY; l_[r] = 0.0f; }

    for (int kt = 0; kt <= qt; ++kt) {
        // stage V^T: per instruction, row uniform, col=lane -> conflict-free
        #pragma unroll
        for (int i = 0; i < 2; ++i) {
            int chunk = tid + 256 * i;             // 0..511
            int s = chunk & 63;
            int e0 = (chunk >> 6) * 8;
            bf16x8 v = *(const bf16x8*)(qkvb +
                (size_t)(b * TT + kt * 64 + s) * D3 + 2 * DM + h * DHD + e0);
            #pragma unroll
            for (int j = 0; j < 8; ++j) Vt[e0 + j][s] = ((unsigned short*)&v)[j];
        }
        __syncthreads();

        // QK^T: K B-frags straight from global (col = l15, d = dt*32+g*8+i)
        float s4[4][4];
        #pragma unroll
        for (int kvt = 0; kvt < 4; ++kvt) {
            const unsigned short* krow = qkvb +
                (size_t)(b * TT + kt * 64 + kvt * 16 + l15) * D3 + DM + h * DHD;
            bf16x8 kb0 = *(const bf16x8*)(krow + g * 8);
            bf16x8 kb1 = *(const bf16x8*)(krow + 32 + g * 8);
            f32x4 acc = {};
            acc = __builtin_amdgcn_mfma_f32_16x16x32_bf16(qf0, kb0, acc, 0, 0, 0);
            acc = __builtin_amdgcn_mfma_f32_16x16x32_bf16(qf1, kb1, acc, 0, 0, 0);
            #pragma unroll
            for (int r = 0; r < 4; ++r) s4[kvt][r] = acc[r] * SCALE_ATT;
        }
        if (kt == qt) {   // causal mask on diagonal tile
            #pragma unroll
            for (int kvt = 0; kvt < 4; ++kvt) {
                int kvg = kt * 64 + kvt * 16 + l15;
                #pragma unroll
                for (int r = 0; r < 4; ++r)
                    if (kvg > q0 + 4 * g + r) s4[kvt][r] = -INFINITY;
            }
        }

        // online softmax (rows live on 16-lane groups: row = 4g+r, col = l15)
        float p[4][4];
        #pragma unroll
        for (int r = 0; r < 4; ++r) {
            float mx = fmaxf(fmaxf(s4[0][r], s4[1][r]), fmaxf(s4[2][r], s4[3][r]));
            #pragma unroll
            for (int off = 8; off >= 1; off >>= 1)
                mx = fmaxf(mx, __shfl_xor(mx, off));
            float mn = fmaxf(m_[r], mx);
            float sc = expf(m_[r] - mn);
            float sum = 0.0f;
            #pragma unroll
            for (int kvt = 0; kvt < 4; ++kvt) {
                float pv = expf(s4[kvt][r] - mn);
                p[kvt][r] = pv; sum += pv;
            }
            #pragma unroll
            for (int off = 8; off >= 1; off >>= 1)
                sum += __shfl_xor(sum, off);
            l_[r] = l_[r] * sc + sum;
            m_[r] = mn;
            #pragma unroll
            for (int et = 0; et < 4; ++et) o[et][r] *= sc;
        }

        // P -> per-wave LDS (bf16), then PV MFMA
        #pragma unroll
        for (int kvt = 0; kvt < 4; ++kvt)
            #pragma unroll
            for (int r = 0; r < 4; ++r)
                Pl[wave][4 * g + r][kvt * 16 + l15] = f2b(p[kvt][r]);

        #pragma unroll
        for (int kh = 0; kh < 2; ++kh) {
            bf16x8 pa = *(const bf16x8*)(&Pl[wave][l15][kh * 32 + g * 8]);
            #pragma unroll
            for (int et = 0; et < 4; ++et) {
                bf16x8 vb = *(const bf16x8*)(&Vt[et * 16 + l15][kh * 32 + g * 8]);
                o[et] = __builtin_amdgcn_mfma_f32_16x16x32_bf16(pa, vb, o[et], 0, 0, 0);
            }
        }
        __syncthreads();   // before next iteration overwrites Vt
    }

    #pragma unroll
    for (int r = 0; r < 4; ++r) {
        float inv = 1.0f / l_[r];
        int row = b * TT + q0 + 4 * g + r;
        #pragma unroll
        for (int et = 0; et < 4; ++et)
            ab[(size_t)row * DM + h * DHD + et * 16 + l15] = f2b(o[et][r] * inv);
    }
}

// ---------------------------------------------------------------------------
// x[row] += LayerNorm(tin[row]) * g + b ; also writes bf16 copy of new x
// ---------------------------------------------------------------------------
__global__ __launch_bounds__(256) void ln_residual_kernel(
        float* __restrict__ x, const float* __restrict__ tin,
        const float* __restrict__ g, const float* __restrict__ b,
        unsigned short* __restrict__ xb) {
    const int row = blockIdx.x;
    const float* tr = tin + (size_t)row * DM;
    const int c0 = threadIdx.x;
    float v0 = tr[c0], v1 = tr[c0 + 256], v2 = tr[c0 + 512];
    __shared__ float red[256];

    red[threadIdx.x] = v0 + v1 + v2; __syncthreads();
    for (int off = 128; off > 0; off >>= 1) {
        if (threadIdx.x < off) red[threadIdx.x] += red[threadIdx.x + off];
        __syncthreads();
    }
    const float mean = red[0] * (1.0f / DM); __syncthreads();

    float d0 = v0 - mean, d1 = v1 - mean, d2 = v2 - mean;
    red[threadIdx.x] = d0 * d0 + d1 * d1 + d2 * d2; __syncthreads();
    for (int off = 128; off > 0; off >>= 1) {
        if (threadIdx.x < off) red[threadIdx.x] += red[threadIdx.x + off];
        __syncthreads();
    }
    const float var = red[0] * (1.0f / DM);
    const float inv = 1.0f / sqrtf(var + EPSF);

    float* xr = x + (size_t)row * DM;
    unsigned short* xbr = xb + (size_t)row * DM;
    float n0 = xr[c0]       + d0 * inv * g[c0]       + b[c0];
    float n1 = xr[c0 + 256] + d1 * inv * g[c0 + 256] + b[c0 + 256];
    float n2 = xr[c0 + 512] + d2 * inv * g[c0 + 512] + b[c0 + 512];
    xr[c0] = n0;       xbr[c0] = f2b(n0);
    xr[c0 + 256] = n1; xbr[c0 + 256] = f2b(n1);
    xr[c0 + 512] = n2; xbr[c0 + 512] = f2b(n2);
}

// ---------------------------------------------------------------------------
extern "C" void kernel_launch(void* const* d_in, const int* in_sizes, int n_in,
                              void* d_out, int out_size, void* d_ws, size_t ws_size,
                              hipStream_t stream) {
    const int*   tokens = (const int*)d_in[0];
    const float* embed  = (const float*)d_in[1];
    const float* Wq  = (const float*)d_in[2];
    const float* Wk  = (const float*)d_in[3];
    const float* Wv  = (const float*)d_in[4];
    const float* Wo  = (const float*)d_in[5];
    const float* bo  = (const float*)d_in[6];
    const float* g1  = (const float*)d_in[7];
    const float* b1  = (const float*)d_in[8];
    const float* W1  = (const float*)d_in[9];
    const float* bf1 = (const float*)d_in[10];
    const float* W2  = (const float*)d_in[11];
    const float* bf2 = (const float*)d_in[12];
    const float* g2  = (const float*)d_in[13];
    const float* b2  = (const float*)d_in[14];
    const float* Wout = (const float*)d_in[15];
    const float* bout = (const float*)d_in[16];
    float* out = (float*)d_out;

    // Workspace layout (~107 MB).  U region (2048*2304*2 B) time-shared:
    //   qkvb (bf16, QKV->attn)  and  t1 (f32, Wo/FFN2 -> LN) never overlap.
    float* x = (float*)d_ws;                                  // [2048][768] f32
    float* t1 = x + (size_t)BTT * DM;                         // f32 view of U
    unsigned short* qkvb = (unsigned short*)t1;               // bf16 view of U
    unsigned short* xb    = (unsigned short*)((char*)t1 + (size_t)BTT * D3 * 2);
    unsigned short* abt1b = xb + (size_t)BTT * DM;            // ab / t1b (time-shared)
    unsigned short* wqkvT = abt1b + (size_t)BTT * DM;         // [12][2304][768]
    unsigned short* woT   = wqkvT + (size_t)NL * D3 * DM;     // [12][768][768]
    unsigned short* w1T   = woT + (size_t)NL * DM * DM;
    unsigned short* w2T   = w1T + (size_t)NL * DM * DM;
    // WoutT [32000][768] bf16 overlays wqkvT+woT (dead after layer loop)
    unsigned short* woutT = wqkvT;

    embed_pos_kernel<<<BTT, 256, 0, stream>>>(tokens, embed, x, xb);
    repack_qkvT_all_kernel<<<(NL * D3 * 96) / 256, 256, 0, stream>>>(Wq, Wk, Wv, wqkvT);
    transconv3_all_kernel<<<dim3(DM / 64, DM / 64, 3 * NL), 256, 0, stream>>>(
        Wo, W1, W2, woT, w1T, w2T);

    for (int l = 0; l < NL; ++l) {
        gemm_mfma_kernel<false, false, true><<<dim3(D3 / 128, BTT / 128), 256, 0, stream>>>(
            xb, wqkvT + (size_t)l * D3 * DM, qkvb, nullptr, BTT, D3, DM);
        attn_flash_kernel<<<dim3(8, BB * NH), 256, 0, stream>>>(qkvb, abt1b);
        gemm_mfma_kernel<false, true, false><<<dim3(DM / 128, BTT / 128), 256, 0, stream>>>(
            abt1b, woT + (size_t)l * DM * DM, t1, bo + (size_t)l * DM, BTT, DM, DM);
        ln_residual_kernel<<<BTT, 256, 0, stream>>>(x, t1, g1 + (size_t)l * DM, b1 + (size_t)l * DM, xb);
        gemm_mfma_kernel<true, true, true><<<dim3(DM / 128, BTT / 128), 256, 0, stream>>>(
            xb, w1T + (size_t)l * DM * DM, abt1b, bf1 + (size_t)l * DM, BTT, DM, DM);
        gemm_mfma_kernel<false, true, false><<<dim3(DM / 128, BTT / 128), 256, 0, stream>>>(
            abt1b, w2T + (size_t)l * DM * DM, t1, bf2 + (size_t)l * DM, BTT, DM, DM);
        ln_residual_kernel<<<BTT, 256, 0, stream>>>(x, t1, g2 + (size_t)l * DM, b2 + (size_t)l * DM, xb);
    }

    transconv_kernel<<<dim3(VSZ / 64, DM / 64), 256, 0, stream>>>(Wout, woutT, DM, VSZ);
    gemm_mfma_kernel<false, true, false><<<dim3(VSZ / 128, BTT / 128), 256, 0, stream>>>(
        xb, woutT, out, bout, BTT, VSZ, DM);
}